// Round 1
// baseline (2774.426 us; speedup 1.0000x reference)
//
#include <hip/hip_runtime.h>
#include <cstdint>
#include <cstddef>

#define Bq 4
#define T 2048
#define Dm 768
#define H 8
#define HD 96
#define BH (Bq*H)                 // 32
#define QBUF ((size_t)BH*T*HD)    // 6,291,456 elements per q/k/v buffer
#define SCALE 0.1020620726159658f // 96^-0.5

// ---------------------------------------------------------------------------
// Tiled f32 GEMM:  C[m,n] = sum_k A[m,k] * Bw[n,k]   (A:[M,K], Bw:[N,K] row-major)
// BM=BN=128, BK=16, 256 threads, 8x8 micro-tile per thread.
// SCATTER=true: N==2304; output element (m, e) is scattered into q/k/v buffers
//   laid out as [3][BH][T][HD] starting at qkv_base.
// SCATTER=false: plain row-major store to C[M,N].
// ---------------------------------------------------------------------------
template <bool SCATTER>
__global__ __launch_bounds__(256)
void gemm_nt(const float* __restrict__ A, const float* __restrict__ Bw,
             float* __restrict__ qkv_base, float* __restrict__ C,
             int M, int N, int K)
{
    __shared__ float As[128][17];
    __shared__ float Bs[128][17];
    const int tid = threadIdx.x;
    const int tx = tid & 15;          // 0..15  (n direction)
    const int ty = tid >> 4;          // 0..15  (m direction)
    const int m0 = blockIdx.y * 128;
    const int n0 = blockIdx.x * 128;

    float acc[8][8];
#pragma unroll
    for (int i = 0; i < 8; ++i)
#pragma unroll
        for (int j = 0; j < 8; ++j) acc[i][j] = 0.f;

    const int lr = tid >> 4;   // row within load pass (0..15)
    const int lc = tid & 15;   // k offset (0..15)

    for (int k0 = 0; k0 < K; k0 += 16) {
#pragma unroll
        for (int p = 0; p < 8; ++p) {
            As[lr + p * 16][lc] = A[(size_t)(m0 + lr + p * 16) * K + k0 + lc];
            Bs[lr + p * 16][lc] = Bw[(size_t)(n0 + lr + p * 16) * K + k0 + lc];
        }
        __syncthreads();
#pragma unroll
        for (int kk = 0; kk < 16; ++kk) {
            float a[8], b[8];
#pragma unroll
            for (int i = 0; i < 8; ++i) a[i] = As[ty * 8 + i][kk];
#pragma unroll
            for (int j = 0; j < 8; ++j) b[j] = Bs[tx * 8 + j][kk];
#pragma unroll
            for (int i = 0; i < 8; ++i)
#pragma unroll
                for (int j = 0; j < 8; ++j) acc[i][j] += a[i] * b[j];
        }
        __syncthreads();
    }

#pragma unroll
    for (int i = 0; i < 8; ++i) {
        const int m = m0 + ty * 8 + i;
        if (SCATTER) {
            const int b_ = m / T, t_ = m % T;
#pragma unroll
            for (int j = 0; j < 8; ++j) {
                const int e = n0 + tx * 8 + j;
                const int c = e / Dm;         // 0:q 1:k 2:v
                const int rem = e - c * Dm;
                const int h = rem / HD;
                const int d = rem - h * HD;
                qkv_base[(size_t)c * QBUF +
                         (((size_t)(b_ * H + h)) * T + t_) * HD + d] = acc[i][j];
            }
        } else {
#pragma unroll
            for (int j = 0; j < 8; ++j) {
                C[(size_t)m * N + (n0 + tx * 8 + j)] = acc[i][j];
            }
        }
    }
}

// ---------------------------------------------------------------------------
// Flash-style causal attention, f32.
// One block (4 waves) handles 4 consecutive query rows of one (b,h).
// K/V staged in LDS in 64-row chunks (stride padded to 97 -> conflict-free).
// Online softmax per wave; each lane accumulates output dims d=lane and
// d=64+(lane&31)  (only lanes<32 write the second).
// Q layout: [BH][T][HD]; output written as [B][T][H*HD] = [B*T, 768].
// ---------------------------------------------------------------------------
__global__ __launch_bounds__(256)
void attn_flash(const float* __restrict__ Q, const float* __restrict__ Kb,
                const float* __restrict__ V, float* __restrict__ Out)
{
    __shared__ float Kl[64][97];
    __shared__ float Vl[64][97];
    __shared__ float Ps[4][64];
    __shared__ float Qs[4][HD];

    const int tid  = threadIdx.x;
    const int lane = tid & 63;
    const int wid  = tid >> 6;
    const int blk  = blockIdx.x;                // 0 .. BH*T/4-1
    const int bh   = blk / (T / 4);
    const int q0   = (blk % (T / 4)) * 4;
    const int qi   = q0 + wid;

    const float* qp = Q + ((size_t)bh * T + qi) * HD;
    for (int d = lane; d < HD; d += 64) Qs[wid][d] = qp[d];
    __syncthreads();

    float m_run = -1e30f, l_run = 0.f;
    float acc0 = 0.f, acc1 = 0.f;
    const int qmax   = q0 + 3;
    const int nchunk = (qmax + 64) / 64;        // ceil((qmax+1)/64)

    for (int c = 0; c < nchunk; ++c) {
        const int kbase = c * 64;
        // cooperative K/V chunk load (contiguous, coalesced)
        {
            const float* kp = Kb + ((size_t)bh * T + kbase) * HD;
            const float* vp = V  + ((size_t)bh * T + kbase) * HD;
            for (int l = tid; l < 64 * HD; l += 256) {
                const int r = l / HD, col = l - r * HD;
                Kl[r][col] = kp[l];
                Vl[r][col] = vp[l];
            }
        }
        __syncthreads();

        // score for key kbase+lane
        const int j = kbase + lane;
        float s = -1e30f;
        if (j <= qi) {
            float d0 = 0.f;
#pragma unroll
            for (int d = 0; d < HD; ++d) d0 += Qs[wid][d] * Kl[lane][d];
            s = d0 * SCALE;
        }
        // wave-wide max
        float cm = s;
#pragma unroll
        for (int off = 32; off; off >>= 1) cm = fmaxf(cm, __shfl_xor(cm, off));
        const float m_new = fmaxf(m_run, cm);
        const float corr  = __expf(m_run - m_new);       // 0 on first chunk
        const float p     = (j <= qi) ? __expf(s - m_new) : 0.f;
        Ps[wid][lane] = p;                                // wave-private row
        float cl = p;
#pragma unroll
        for (int off = 32; off; off >>= 1) cl += __shfl_xor(cl, off);
        l_run = l_run * corr + cl;
        acc0 *= corr;
        acc1 *= corr;
        m_run = m_new;

        // accumulate P @ V from LDS (Ps write->read is same-wave, in-order)
#pragma unroll 4
        for (int jj = 0; jj < 64; ++jj) {
            const float pj = Ps[wid][jj];
            acc0 += pj * Vl[jj][lane];
            acc1 += pj * Vl[jj][64 + (lane & 31)];
        }
        __syncthreads();   // protect Kl/Vl before next chunk's overwrite
    }

    const float inv = 1.f / l_run;
    const int ob = bh / H, oh = bh - ob * H;
    float* op = Out + ((size_t)ob * T + qi) * Dm + oh * HD;
    op[lane] = acc0 * inv;
    if (lane < 32) op[64 + lane] = acc1 * inv;
}

// ---------------------------------------------------------------------------
extern "C" void kernel_launch(void* const* d_in, const int* in_sizes, int n_in,
                              void* d_out, int out_size, void* d_ws, size_t ws_size,
                              hipStream_t stream)
{
    const float* x     = (const float*)d_in[0];   // [B,T,D]
    const float* w_qkv = (const float*)d_in[1];   // [3D, D]
    const float* w_out = (const float*)d_in[2];   // [D, D]
    // d_in[3] = leech kernel: orthogonal -> cancels in q.kT, ignored.

    float* ws = (float*)d_ws;
    float* qb = ws;                // [BH][T][HD]
    float* kb = ws + QBUF;
    float* vb = ws + 2 * QBUF;
    float* ao = ws + 3 * QBUF;     // [B*T, 768]
    float* out = (float*)d_out;

    const int M = Bq * T;          // 8192

    // 1) qkv projection, scatter into q/k/v buffers
    gemm_nt<true><<<dim3((3 * Dm) / 128, M / 128), dim3(256), 0, stream>>>(
        x, w_qkv, ws, nullptr, M, 3 * Dm, Dm);

    // 2) causal flash attention
    attn_flash<<<dim3(BH * T / 4), dim3(256), 0, stream>>>(qb, kb, vb, ao);

    // 3) output projection
    gemm_nt<false><<<dim3(Dm / 128, M / 128), dim3(256), 0, stream>>>(
        ao, w_out, nullptr, out, M, Dm, Dm);
}

// Round 2
// 991.974 us; speedup vs baseline: 2.7969x; 2.7969x over previous
//
#include <hip/hip_runtime.h>
#include <hip/hip_bf16.h>
#include <cstdint>
#include <cstddef>

#define Bq 4
#define T 2048
#define Dm 768
#define H 8
#define HD 96
#define BH (Bq*H)                 // 32
#define QBUF ((size_t)BH*T*HD)    // elements per q/k/v buffer
#define SCALE 0.1020620726159658f // 96^-0.5

typedef unsigned int u32;
typedef unsigned long long u64;
typedef _Float16 f16x8 __attribute__((ext_vector_type(8)));
typedef _Float16 f16x2 __attribute__((ext_vector_type(2)));
typedef float f32x4 __attribute__((ext_vector_type(4)));

// ---------------------------------------------------------------------------
// Tiled f32 GEMM:  C[m,n] = sum_k A[m,k] * Bw[n,k]
// SCATTER=true: scatter-convert output into fp16 q/k/v buffers [3][BH][T][HD].
// ---------------------------------------------------------------------------
template <bool SCATTER>
__global__ __launch_bounds__(256)
void gemm_nt(const float* __restrict__ A, const float* __restrict__ Bw,
             _Float16* __restrict__ qkv_base, float* __restrict__ C,
             int M, int N, int K)
{
    __shared__ float As[128][17];
    __shared__ float Bs[128][17];
    const int tid = threadIdx.x;
    const int tx = tid & 15;
    const int ty = tid >> 4;
    const int m0 = blockIdx.y * 128;
    const int n0 = blockIdx.x * 128;

    float acc[8][8];
#pragma unroll
    for (int i = 0; i < 8; ++i)
#pragma unroll
        for (int j = 0; j < 8; ++j) acc[i][j] = 0.f;

    const int lr = tid >> 4;
    const int lc = tid & 15;

    for (int k0 = 0; k0 < K; k0 += 16) {
#pragma unroll
        for (int p = 0; p < 8; ++p) {
            As[lr + p * 16][lc] = A[(size_t)(m0 + lr + p * 16) * K + k0 + lc];
            Bs[lr + p * 16][lc] = Bw[(size_t)(n0 + lr + p * 16) * K + k0 + lc];
        }
        __syncthreads();
#pragma unroll
        for (int kk = 0; kk < 16; ++kk) {
            float a[8], b[8];
#pragma unroll
            for (int i = 0; i < 8; ++i) a[i] = As[ty * 8 + i][kk];
#pragma unroll
            for (int j = 0; j < 8; ++j) b[j] = Bs[tx * 8 + j][kk];
#pragma unroll
            for (int i = 0; i < 8; ++i)
#pragma unroll
                for (int j = 0; j < 8; ++j) acc[i][j] += a[i] * b[j];
        }
        __syncthreads();
    }

#pragma unroll
    for (int i = 0; i < 8; ++i) {
        const int m = m0 + ty * 8 + i;
        if (SCATTER) {
            const int b_ = m / T, t_ = m % T;
#pragma unroll
            for (int j = 0; j < 8; ++j) {
                const int e = n0 + tx * 8 + j;
                const int c = e / Dm;
                const int rem = e - c * Dm;
                const int h = rem / HD;
                const int d = rem - h * HD;
                qkv_base[(size_t)c * QBUF +
                         (((size_t)(b_ * H + h)) * T + t_) * HD + d] =
                    (_Float16)acc[i][j];
            }
        } else {
#pragma unroll
            for (int j = 0; j < 8; ++j)
                C[(size_t)m * N + (n0 + tx * 8 + j)] = acc[i][j];
        }
    }
}

// ---------------------------------------------------------------------------
// MFMA flash attention (fp16 in, f32 out), causal.
// Block = 4 waves, 128 q rows (32/wave, 2 subtiles of 16). KV tiles of 32.
// S^T = mfma(K, Q) so softmax over k is per-lane (q = lane&15).
// ---------------------------------------------------------------------------
__global__ __launch_bounds__(256)
void attn_mfma(const _Float16* __restrict__ Qg, const _Float16* __restrict__ Kg,
               const _Float16* __restrict__ Vg, float* __restrict__ Out)
{
    __shared__ _Float16 Qs[128][104];   // stride 104 -> conflict-free b128 reads
    __shared__ _Float16 Ks[32][104];
    __shared__ _Float16 Vt[96][40];     // V transposed: Vt[d][k]
    __shared__ _Float16 Pl[4][32][40];  // per-wave P staging

    const int tid  = threadIdx.x;
    const int lane = tid & 63;
    const int wid  = tid >> 6;
    const int lg   = lane >> 4;   // 0..3
    const int li   = lane & 15;

    const int bh = blockIdx.x & 31;
    const int qt_blk = (T / 128 - 1) - (blockIdx.x >> 5);  // heavy tiles first
    const int q0 = qt_blk * 128;

    // stage Q tile (128 x 96 fp16), coalesced u64
    {
        const u64* src = reinterpret_cast<const u64*>(Qg + ((size_t)bh * T + q0) * HD);
        for (int l = tid; l < 128 * 24; l += 256) {
            const int r = l / 24, c = l % 24;
            *reinterpret_cast<u64*>(&Qs[r][c * 4]) = src[l];
        }
    }
    __syncthreads();

    // hoist Q B-frags: qf[subtile][k-chunk]
    f16x8 qf[2][3];
#pragma unroll
    for (int qt = 0; qt < 2; ++qt)
#pragma unroll
        for (int ch = 0; ch < 3; ++ch)
            qf[qt][ch] = *reinterpret_cast<const f16x8*>(
                &Qs[wid * 32 + qt * 16 + li][ch * 32 + lg * 8]);

    f32x4 acc[2][6];
#pragma unroll
    for (int qt = 0; qt < 2; ++qt)
#pragma unroll
        for (int dt = 0; dt < 6; ++dt) acc[qt][dt] = (f32x4)0.f;
    float m_run[2] = {-1e30f, -1e30f};
    float l_run[2] = {0.f, 0.f};

    const int ntiles = q0 / 32 + 4;
    for (int t = 0; t < ntiles; ++t) {
        const int kb = t * 32;
        __syncthreads();  // previous tile's LDS reads done
        // stage K (32 x 96), coalesced u64
        {
            const u64* src = reinterpret_cast<const u64*>(Kg + ((size_t)bh * T + kb) * HD);
            for (int l = tid; l < 32 * 24; l += 256) {
                const int r = l / 24, c = l % 24;
                *reinterpret_cast<u64*>(&Ks[r][c * 4]) = src[l];
            }
        }
        // stage V transposed (row r = tid&31, column chunk cc = tid>>5)
        {
            const u64* src = reinterpret_cast<const u64*>(Vg + ((size_t)bh * T + kb) * HD);
            const int r = tid & 31, cc = tid >> 5;
#pragma unroll
            for (int i = 0; i < 3; ++i) {
                u64 v = src[r * 24 + cc * 3 + i];
                const _Float16* pv = reinterpret_cast<const _Float16*>(&v);
                const int c0 = (cc * 3 + i) * 4;
#pragma unroll
                for (int j = 0; j < 4; ++j) Vt[c0 + j][r] = pv[j];
            }
        }
        __syncthreads();

        // K A-frags and V B-frags (shared across both q subtiles)
        f16x8 kf[2][3];
#pragma unroll
        for (int kt = 0; kt < 2; ++kt)
#pragma unroll
            for (int ch = 0; ch < 3; ++ch)
                kf[kt][ch] = *reinterpret_cast<const f16x8*>(
                    &Ks[kt * 16 + li][ch * 32 + lg * 8]);
        f16x8 vf[6];
#pragma unroll
        for (int dt = 0; dt < 6; ++dt)
            vf[dt] = *reinterpret_cast<const f16x8*>(&Vt[dt * 16 + li][lg * 8]);

#pragma unroll
        for (int qt = 0; qt < 2; ++qt) {
            const int qmax = q0 + wid * 32 + qt * 16 + 15;
            if (kb > qmax) continue;   // wave-uniform skip

            f32x4 st[2] = {(f32x4)0.f, (f32x4)0.f};
#pragma unroll
            for (int kt = 0; kt < 2; ++kt)
#pragma unroll
                for (int ch = 0; ch < 3; ++ch)
                    st[kt] = __builtin_amdgcn_mfma_f32_16x16x32_f16(
                        kf[kt][ch], qf[qt][ch], st[kt], 0, 0, 0);

            // mask + scale + row max (q = lane&15, k = kb + kt*16 + lg*4 + rr)
            const int qg = q0 + wid * 32 + qt * 16 + li;
            float s[8];
            float m8 = -1e30f;
#pragma unroll
            for (int kt = 0; kt < 2; ++kt)
#pragma unroll
                for (int rr = 0; rr < 4; ++rr) {
                    const int kg = kb + kt * 16 + lg * 4 + rr;
                    const float v = (kg <= qg) ? st[kt][rr] * SCALE : -1e30f;
                    s[kt * 4 + rr] = v;
                    m8 = fmaxf(m8, v);
                }
            m8 = fmaxf(m8, __shfl_xor(m8, 16));
            m8 = fmaxf(m8, __shfl_xor(m8, 32));
            const float m_new = fmaxf(m_run[qt], m8);
            const float corr = __expf(m_run[qt] - m_new);
            m_run[qt] = m_new;

            float p[8], ls = 0.f;
#pragma unroll
            for (int i = 0; i < 8; ++i) { p[i] = __expf(s[i] - m_new); ls += p[i]; }
            ls += __shfl_xor(ls, 16);
            ls += __shfl_xor(ls, 32);
            l_run[qt] = l_run[qt] * corr + ls;

            // write P (fp16 pairs) to wave-private LDS
#pragma unroll
            for (int kt = 0; kt < 2; ++kt) {
                f16x2 a, b;
                a[0] = (_Float16)p[kt * 4 + 0]; a[1] = (_Float16)p[kt * 4 + 1];
                b[0] = (_Float16)p[kt * 4 + 2]; b[1] = (_Float16)p[kt * 4 + 3];
                u32* dst = reinterpret_cast<u32*>(&Pl[wid][qt * 16 + li][kt * 16 + lg * 4]);
                dst[0] = __builtin_bit_cast(u32, a);
                dst[1] = __builtin_bit_cast(u32, b);
            }

            // rescale accumulators (rows q' = lg*4+rr)
            float cr[4];
#pragma unroll
            for (int rr = 0; rr < 4; ++rr) cr[rr] = __shfl(corr, lg * 4 + rr);
#pragma unroll
            for (int dt = 0; dt < 6; ++dt)
#pragma unroll
                for (int rr = 0; rr < 4; ++rr) acc[qt][dt][rr] *= cr[rr];

            // PV: A = P[16q x 32k] (same-wave LDS, in-order), B = V
            const f16x8 pf = *reinterpret_cast<const f16x8*>(
                &Pl[wid][qt * 16 + li][lg * 8]);
#pragma unroll
            for (int dt = 0; dt < 6; ++dt)
                acc[qt][dt] = __builtin_amdgcn_mfma_f32_16x16x32_f16(
                    pf, vf[dt], acc[qt][dt], 0, 0, 0);
        }
    }

    // epilogue: divide by l, store f32 to Out[B][T][768]
    const int ob = bh >> 3, oh = bh & 7;
#pragma unroll
    for (int qt = 0; qt < 2; ++qt)
#pragma unroll
        for (int rr = 0; rr < 4; ++rr) {
            const float linv = 1.0f / __shfl(l_run[qt], lg * 4 + rr);
            const int qg = q0 + wid * 32 + qt * 16 + lg * 4 + rr;
            float* op = Out + ((size_t)(ob * T + qg)) * Dm + oh * HD;
#pragma unroll
            for (int dt = 0; dt < 6; ++dt)
                op[dt * 16 + li] = acc[qt][dt][rr] * linv;
        }
}

// ---------------------------------------------------------------------------
extern "C" void kernel_launch(void* const* d_in, const int* in_sizes, int n_in,
                              void* d_out, int out_size, void* d_ws, size_t ws_size,
                              hipStream_t stream)
{
    const float* x     = (const float*)d_in[0];
    const float* w_qkv = (const float*)d_in[1];
    const float* w_out = (const float*)d_in[2];
    // d_in[3] = leech kernel: orthogonal -> cancels in q.kT, ignored.

    _Float16* qb = (_Float16*)d_ws;
    _Float16* kb = qb + QBUF;
    _Float16* vb = kb + QBUF;
    float* ao = (float*)(qb + 3 * QBUF);   // [B*T, 768]
    float* out = (float*)d_out;

    const int M = Bq * T;  // 8192

    // 1) qkv projection -> fp16 q/k/v
    gemm_nt<true><<<dim3((3 * Dm) / 128, M / 128), dim3(256), 0, stream>>>(
        x, w_qkv, qb, nullptr, M, 3 * Dm, Dm);

    // 2) MFMA causal flash attention
    attn_mfma<<<dim3(BH * (T / 128)), dim3(256), 0, stream>>>(qb, kb, vb, ao);

    // 3) output projection
    gemm_nt<false><<<dim3(Dm / 128, M / 128), dim3(256), 0, stream>>>(
        ao, w_out, nullptr, out, M, Dm, Dm);
}

// Round 3
// 279.448 us; speedup vs baseline: 9.9282x; 3.5498x over previous
//
#include <hip/hip_runtime.h>
#include <hip/hip_bf16.h>
#include <cstdint>
#include <cstddef>

#define Bq 4
#define T 2048
#define Dm 768
#define H 8
#define HD 96
#define BH (Bq*H)                 // 32
#define QBUF ((size_t)BH*T*HD)    // elements per q/k/v buffer
#define SCALE 0.1020620726159658f // 96^-0.5

typedef unsigned int u32;
typedef unsigned long long u64;
typedef _Float16 f16x8 __attribute__((ext_vector_type(8)));
typedef _Float16 f16x4 __attribute__((ext_vector_type(4)));
typedef _Float16 f16x2 __attribute__((ext_vector_type(2)));
typedef float f32x4 __attribute__((ext_vector_type(4)));

// ---------------------------------------------------------------------------
// f32 -> f16 convert, vectorized (float4 in, f16x4 out)
// ---------------------------------------------------------------------------
__global__ __launch_bounds__(256)
void cvt_f16(const float* __restrict__ in, _Float16* __restrict__ out, int n4)
{
    const int i = blockIdx.x * 256 + threadIdx.x;
    if (i < n4) {
        const float4 v = reinterpret_cast<const float4*>(in)[i];
        f16x4 h;
        h[0] = (_Float16)v.x; h[1] = (_Float16)v.y;
        h[2] = (_Float16)v.z; h[3] = (_Float16)v.w;
        reinterpret_cast<f16x4*>(out)[i] = h;
    }
}

// ---------------------------------------------------------------------------
// fp16 MFMA GEMM:  C[m,n] = sum_k A[m,k]*Bw[n,k], K=768, BM=BN=128, BK=32.
// 4 waves, each computes 64x64 (4x4 frags of 16x16), mfma_f32_16x16x32_f16.
// LDS tiles in k-chunk-plane layout [4][128][8] fp16 (linear, fed by
// global_load_lds width=16; frag reads are contiguous 256B per quarter-wave).
// SCATTER=true: convert+scatter output into fp16 q/k/v [3][BH][T][HD].
// SCATTER=false: f32 store to C[M,N].
// ---------------------------------------------------------------------------
template <bool SCATTER>
__global__ __launch_bounds__(256)
void gemm_mfma(const _Float16* __restrict__ A, const _Float16* __restrict__ Bw,
               _Float16* __restrict__ qkv_base, float* __restrict__ C,
               int N)
{
    constexpr int K = Dm;
    __shared__ _Float16 As[4 * 128 * 8];
    __shared__ _Float16 Bs[4 * 128 * 8];

    const int tid  = threadIdx.x;
    const int lane = tid & 63;
    const int wid  = tid >> 6;
    const int li   = lane & 15;
    const int lg   = lane >> 4;
    const int wr   = wid >> 1;        // wave row (0..1)
    const int wc   = wid & 1;         // wave col (0..1)
    const int m0   = blockIdx.y * 128;
    const int n0   = blockIdx.x * 128;

    f32x4 acc[4][4];
#pragma unroll
    for (int i = 0; i < 4; ++i)
#pragma unroll
        for (int j = 0; j < 4; ++j) acc[i][j] = (f32x4)0.f;

    // per-lane slot decomposition for staging (2 instrs per wave per matrix)
    const int s0   = wid * 128 + lane;        // slots s0, s0+64
    for (int k0 = 0; k0 < K; k0 += 32) {
#pragma unroll
        for (int i = 0; i < 2; ++i) {
            const int s = s0 + i * 64;
            const int row = s & 127, chunk = s >> 7;
            const _Float16* ga = A + (size_t)(m0 + row) * K + k0 + chunk * 8;
            const _Float16* gb = Bw + (size_t)(n0 + row) * K + k0 + chunk * 8;
            __builtin_amdgcn_global_load_lds(
                (const __attribute__((address_space(1))) void*)ga,
                (__attribute__((address_space(3))) void*)&As[(wid * 128 + i * 64) * 8],
                16, 0, 0);
            __builtin_amdgcn_global_load_lds(
                (const __attribute__((address_space(1))) void*)gb,
                (__attribute__((address_space(3))) void*)&Bs[(wid * 128 + i * 64) * 8],
                16, 0, 0);
        }
        __syncthreads();   // drains vmcnt before reads

        f16x8 af[4], bf[4];
#pragma unroll
        for (int i = 0; i < 4; ++i)
            af[i] = *reinterpret_cast<const f16x8*>(
                &As[(lg * 128 + wr * 64 + i * 16 + li) * 8]);
#pragma unroll
        for (int j = 0; j < 4; ++j)
            bf[j] = *reinterpret_cast<const f16x8*>(
                &Bs[(lg * 128 + wc * 64 + j * 16 + li) * 8]);
#pragma unroll
        for (int i = 0; i < 4; ++i)
#pragma unroll
            for (int j = 0; j < 4; ++j)
                acc[i][j] = __builtin_amdgcn_mfma_f32_16x16x32_f16(
                    af[i], bf[j], acc[i][j], 0, 0, 0);
        __syncthreads();   // all reads done before next stage overwrites
    }

    // epilogue: D row = m (frag first operand), col = n (lane&15)
#pragma unroll
    for (int i = 0; i < 4; ++i) {
#pragma unroll
        for (int r = 0; r < 4; ++r) {
            const int m = m0 + wr * 64 + i * 16 + lg * 4 + r;
            if (SCATTER) {
                const int b_ = m >> 11, t_ = m & 2047;
#pragma unroll
                for (int j = 0; j < 4; ++j) {
                    const int e = n0 + wc * 64 + j * 16 + li;
                    const int c = e / Dm;
                    const int rem = e - c * Dm;
                    const int h = rem / HD;
                    const int d = rem - h * HD;
                    qkv_base[(size_t)c * QBUF +
                             (((size_t)(b_ * H + h)) * T + t_) * HD + d] =
                        (_Float16)acc[i][j][r];
                }
            } else {
#pragma unroll
                for (int j = 0; j < 4; ++j) {
                    const int n = n0 + wc * 64 + j * 16 + li;
                    C[(size_t)m * N + n] = acc[i][j][r];
                }
            }
        }
    }
}

// ---------------------------------------------------------------------------
// MFMA flash attention (fp16 in, fp16 out), causal. Unchanged structure.
// ---------------------------------------------------------------------------
__global__ __launch_bounds__(256)
void attn_mfma(const _Float16* __restrict__ Qg, const _Float16* __restrict__ Kg,
               const _Float16* __restrict__ Vg, _Float16* __restrict__ Out)
{
    __shared__ _Float16 Qs[128][104];
    __shared__ _Float16 Ks[32][104];
    __shared__ _Float16 Vt[96][40];
    __shared__ _Float16 Pl[4][32][40];

    const int tid  = threadIdx.x;
    const int lane = tid & 63;
    const int wid  = tid >> 6;
    const int lg   = lane >> 4;
    const int li   = lane & 15;

    const int bh = blockIdx.x & 31;
    const int qt_blk = (T / 128 - 1) - (blockIdx.x >> 5);  // heavy tiles first
    const int q0 = qt_blk * 128;

    {
        const u64* src = reinterpret_cast<const u64*>(Qg + ((size_t)bh * T + q0) * HD);
        for (int l = tid; l < 128 * 24; l += 256) {
            const int r = l / 24, c = l % 24;
            *reinterpret_cast<u64*>(&Qs[r][c * 4]) = src[l];
        }
    }
    __syncthreads();

    f16x8 qf[2][3];
#pragma unroll
    for (int qt = 0; qt < 2; ++qt)
#pragma unroll
        for (int ch = 0; ch < 3; ++ch)
            qf[qt][ch] = *reinterpret_cast<const f16x8*>(
                &Qs[wid * 32 + qt * 16 + li][ch * 32 + lg * 8]);

    f32x4 acc[2][6];
#pragma unroll
    for (int qt = 0; qt < 2; ++qt)
#pragma unroll
        for (int dt = 0; dt < 6; ++dt) acc[qt][dt] = (f32x4)0.f;
    float m_run[2] = {-1e30f, -1e30f};
    float l_run[2] = {0.f, 0.f};

    const int ntiles = q0 / 32 + 4;
    for (int t = 0; t < ntiles; ++t) {
        const int kb = t * 32;
        __syncthreads();
        {
            const u64* src = reinterpret_cast<const u64*>(Kg + ((size_t)bh * T + kb) * HD);
            for (int l = tid; l < 32 * 24; l += 256) {
                const int r = l / 24, c = l % 24;
                *reinterpret_cast<u64*>(&Ks[r][c * 4]) = src[l];
            }
        }
        {
            const u64* src = reinterpret_cast<const u64*>(Vg + ((size_t)bh * T + kb) * HD);
            const int r = tid & 31, cc = tid >> 5;
#pragma unroll
            for (int i = 0; i < 3; ++i) {
                u64 v = src[r * 24 + cc * 3 + i];
                const _Float16* pv = reinterpret_cast<const _Float16*>(&v);
                const int c0 = (cc * 3 + i) * 4;
#pragma unroll
                for (int j = 0; j < 4; ++j) Vt[c0 + j][r] = pv[j];
            }
        }
        __syncthreads();

        f16x8 kf[2][3];
#pragma unroll
        for (int kt = 0; kt < 2; ++kt)
#pragma unroll
            for (int ch = 0; ch < 3; ++ch)
                kf[kt][ch] = *reinterpret_cast<const f16x8*>(
                    &Ks[kt * 16 + li][ch * 32 + lg * 8]);
        f16x8 vf[6];
#pragma unroll
        for (int dt = 0; dt < 6; ++dt)
            vf[dt] = *reinterpret_cast<const f16x8*>(&Vt[dt * 16 + li][lg * 8]);

#pragma unroll
        for (int qt = 0; qt < 2; ++qt) {
            const int qmax = q0 + wid * 32 + qt * 16 + 15;
            if (kb > qmax) continue;

            f32x4 st[2] = {(f32x4)0.f, (f32x4)0.f};
#pragma unroll
            for (int kt = 0; kt < 2; ++kt)
#pragma unroll
                for (int ch = 0; ch < 3; ++ch)
                    st[kt] = __builtin_amdgcn_mfma_f32_16x16x32_f16(
                        kf[kt][ch], qf[qt][ch], st[kt], 0, 0, 0);

            const int qg = q0 + wid * 32 + qt * 16 + li;
            float s[8];
            float m8 = -1e30f;
#pragma unroll
            for (int kt = 0; kt < 2; ++kt)
#pragma unroll
                for (int rr = 0; rr < 4; ++rr) {
                    const int kg = kb + kt * 16 + lg * 4 + rr;
                    const float v = (kg <= qg) ? st[kt][rr] * SCALE : -1e30f;
                    s[kt * 4 + rr] = v;
                    m8 = fmaxf(m8, v);
                }
            m8 = fmaxf(m8, __shfl_xor(m8, 16));
            m8 = fmaxf(m8, __shfl_xor(m8, 32));
            const float m_new = fmaxf(m_run[qt], m8);
            const float corr = __expf(m_run[qt] - m_new);
            m_run[qt] = m_new;

            float p[8], ls = 0.f;
#pragma unroll
            for (int i = 0; i < 8; ++i) { p[i] = __expf(s[i] - m_new); ls += p[i]; }
            ls += __shfl_xor(ls, 16);
            ls += __shfl_xor(ls, 32);
            l_run[qt] = l_run[qt] * corr + ls;

#pragma unroll
            for (int kt = 0; kt < 2; ++kt) {
                f16x2 a, b;
                a[0] = (_Float16)p[kt * 4 + 0]; a[1] = (_Float16)p[kt * 4 + 1];
                b[0] = (_Float16)p[kt * 4 + 2]; b[1] = (_Float16)p[kt * 4 + 3];
                u32* dst = reinterpret_cast<u32*>(&Pl[wid][qt * 16 + li][kt * 16 + lg * 4]);
                dst[0] = __builtin_bit_cast(u32, a);
                dst[1] = __builtin_bit_cast(u32, b);
            }

            float cr[4];
#pragma unroll
            for (int rr = 0; rr < 4; ++rr) cr[rr] = __shfl(corr, lg * 4 + rr);
#pragma unroll
            for (int dt = 0; dt < 6; ++dt)
#pragma unroll
                for (int rr = 0; rr < 4; ++rr) acc[qt][dt][rr] *= cr[rr];

            const f16x8 pf = *reinterpret_cast<const f16x8*>(
                &Pl[wid][qt * 16 + li][lg * 8]);
#pragma unroll
            for (int dt = 0; dt < 6; ++dt)
                acc[qt][dt] = __builtin_amdgcn_mfma_f32_16x16x32_f16(
                    pf, vf[dt], acc[qt][dt], 0, 0, 0);
        }
    }

    const int ob = bh >> 3, oh = bh & 7;
#pragma unroll
    for (int qt = 0; qt < 2; ++qt)
#pragma unroll
        for (int rr = 0; rr < 4; ++rr) {
            const float linv = 1.0f / __shfl(l_run[qt], lg * 4 + rr);
            const int qg = q0 + wid * 32 + qt * 16 + lg * 4 + rr;
            _Float16* op = Out + ((size_t)(ob * T + qg)) * Dm + oh * HD;
#pragma unroll
            for (int dt = 0; dt < 6; ++dt)
                op[dt * 16 + li] = (_Float16)(acc[qt][dt][rr] * linv);
        }
}

// ---------------------------------------------------------------------------
extern "C" void kernel_launch(void* const* d_in, const int* in_sizes, int n_in,
                              void* d_out, int out_size, void* d_ws, size_t ws_size,
                              hipStream_t stream)
{
    const float* x     = (const float*)d_in[0];
    const float* w_qkv = (const float*)d_in[1];
    const float* w_out = (const float*)d_in[2];
    // d_in[3] = leech kernel: orthogonal -> cancels in q.kT, ignored.

    _Float16* qb  = (_Float16*)d_ws;
    _Float16* kb  = qb + QBUF;
    _Float16* vb  = kb + QBUF;
    _Float16* aoh = vb + QBUF;                 // [B*T, 768] fp16
    _Float16* xh  = aoh + (size_t)Bq * T * Dm; // [B*T, 768] fp16
    _Float16* wqh = xh + (size_t)Bq * T * Dm;  // [2304, 768]
    _Float16* woh = wqh + (size_t)3 * Dm * Dm; // [768, 768]
    float* out = (float*)d_out;

    const int M = Bq * T;  // 8192

    // 0) convert inputs to fp16
    cvt_f16<<<dim3((M * Dm) / 4 / 256), dim3(256), 0, stream>>>(x, xh, M * Dm / 4);
    cvt_f16<<<dim3((3 * Dm * Dm) / 4 / 256), dim3(256), 0, stream>>>(w_qkv, wqh, 3 * Dm * Dm / 4);
    cvt_f16<<<dim3((Dm * Dm) / 4 / 256), dim3(256), 0, stream>>>(w_out, woh, Dm * Dm / 4);

    // 1) qkv projection (MFMA) -> scatter fp16 q/k/v
    gemm_mfma<true><<<dim3((3 * Dm) / 128, M / 128), dim3(256), 0, stream>>>(
        xh, wqh, qb, nullptr, 3 * Dm);

    // 2) MFMA causal flash attention -> fp16 ao
    attn_mfma<<<dim3(BH * (T / 128)), dim3(256), 0, stream>>>(qb, kb, vb, aoh);

    // 3) output projection (MFMA) -> f32 d_out
    gemm_mfma<false><<<dim3(Dm / 128, M / 128), dim3(256), 0, stream>>>(
        aoh, woh, nullptr, out, Dm);
}

// Round 4
// 231.700 us; speedup vs baseline: 11.9742x; 1.2061x over previous
//
#include <hip/hip_runtime.h>
#include <hip/hip_bf16.h>
#include <cstdint>
#include <cstddef>

#define Bq 4
#define T 2048
#define Dm 768
#define H 8
#define HD 96
#define BH (Bq*H)                 // 32
#define QBUF ((size_t)BH*T*HD)    // elements per q/k/v buffer
// q pre-scaled by HD^-0.5 * log2(e): attention uses exp2 directly
#define QS 0.14724703336f

typedef unsigned int u32;
typedef unsigned long long u64;
typedef _Float16 f16x8 __attribute__((ext_vector_type(8)));
typedef _Float16 f16x4 __attribute__((ext_vector_type(4)));
typedef _Float16 f16x2 __attribute__((ext_vector_type(2)));
typedef float f32x4 __attribute__((ext_vector_type(4)));

// ---------------------------------------------------------------------------
__global__ __launch_bounds__(256)
void cvt_f16(const float* __restrict__ in, _Float16* __restrict__ out, int n4)
{
    const int i = blockIdx.x * 256 + threadIdx.x;
    if (i < n4) {
        const float4 v = reinterpret_cast<const float4*>(in)[i];
        f16x4 h;
        h[0] = (_Float16)v.x; h[1] = (_Float16)v.y;
        h[2] = (_Float16)v.z; h[3] = (_Float16)v.w;
        reinterpret_cast<f16x4*>(out)[i] = h;
    }
}

// ---------------------------------------------------------------------------
// fp16 MFMA GEMM, BM=BN=128, BK=32, 4 waves, 64x64/wave.
// SCATTER=true: scatter into q/k/v [3][BH][T][HD]; q gets *QS (exp2 folding).
// ---------------------------------------------------------------------------
template <bool SCATTER>
__global__ __launch_bounds__(256)
void gemm_mfma(const _Float16* __restrict__ A, const _Float16* __restrict__ Bw,
               _Float16* __restrict__ qkv_base, float* __restrict__ C,
               int N)
{
    constexpr int K = Dm;
    __shared__ _Float16 As[4 * 128 * 8];
    __shared__ _Float16 Bs[4 * 128 * 8];

    const int tid  = threadIdx.x;
    const int lane = tid & 63;
    const int wid  = tid >> 6;
    const int li   = lane & 15;
    const int lg   = lane >> 4;
    const int wr   = wid >> 1;
    const int wc   = wid & 1;
    const int m0   = blockIdx.y * 128;
    const int n0   = blockIdx.x * 128;

    f32x4 acc[4][4];
#pragma unroll
    for (int i = 0; i < 4; ++i)
#pragma unroll
        for (int j = 0; j < 4; ++j) acc[i][j] = (f32x4)0.f;

    const int s0 = wid * 128 + lane;
    for (int k0 = 0; k0 < K; k0 += 32) {
#pragma unroll
        for (int i = 0; i < 2; ++i) {
            const int s = s0 + i * 64;
            const int row = s & 127, chunk = s >> 7;
            const _Float16* ga = A + (size_t)(m0 + row) * K + k0 + chunk * 8;
            const _Float16* gb = Bw + (size_t)(n0 + row) * K + k0 + chunk * 8;
            __builtin_amdgcn_global_load_lds(
                (const __attribute__((address_space(1))) void*)ga,
                (__attribute__((address_space(3))) void*)&As[(wid * 128 + i * 64) * 8],
                16, 0, 0);
            __builtin_amdgcn_global_load_lds(
                (const __attribute__((address_space(1))) void*)gb,
                (__attribute__((address_space(3))) void*)&Bs[(wid * 128 + i * 64) * 8],
                16, 0, 0);
        }
        __syncthreads();

        f16x8 af[4], bf[4];
#pragma unroll
        for (int i = 0; i < 4; ++i)
            af[i] = *reinterpret_cast<const f16x8*>(
                &As[(lg * 128 + wr * 64 + i * 16 + li) * 8]);
#pragma unroll
        for (int j = 0; j < 4; ++j)
            bf[j] = *reinterpret_cast<const f16x8*>(
                &Bs[(lg * 128 + wc * 64 + j * 16 + li) * 8]);
#pragma unroll
        for (int i = 0; i < 4; ++i)
#pragma unroll
            for (int j = 0; j < 4; ++j)
                acc[i][j] = __builtin_amdgcn_mfma_f32_16x16x32_f16(
                    af[i], bf[j], acc[i][j], 0, 0, 0);
        __syncthreads();
    }

#pragma unroll
    for (int i = 0; i < 4; ++i) {
#pragma unroll
        for (int r = 0; r < 4; ++r) {
            const int m = m0 + wr * 64 + i * 16 + lg * 4 + r;
            if (SCATTER) {
                const int b_ = m >> 11, t_ = m & 2047;
#pragma unroll
                for (int j = 0; j < 4; ++j) {
                    const int e = n0 + wc * 64 + j * 16 + li;
                    const int c = e / Dm;
                    const int rem = e - c * Dm;
                    const int h = rem / HD;
                    const int d = rem - h * HD;
                    const float sc = (c == 0) ? QS : 1.f;
                    qkv_base[(size_t)c * QBUF +
                             (((size_t)(b_ * H + h)) * T + t_) * HD + d] =
                        (_Float16)(acc[i][j][r] * sc);
                }
            } else {
#pragma unroll
                for (int j = 0; j < 4; ++j) {
                    const int n = n0 + wc * 64 + j * 16 + li;
                    C[(size_t)m * N + n] = acc[i][j][r];
                }
            }
        }
    }
}

// ---------------------------------------------------------------------------
// MFMA flash attention, causal, fp16 in/out. Q pre-scaled, softmax in exp2.
// Block = 4 waves x 16 q rows (QBLK=64); KV tiles of 32. Grid 1024, heavy 1st.
// Defer-max: skip accumulator rescale while per-tile max growth <= 8 (log2).
// ---------------------------------------------------------------------------
__global__ __launch_bounds__(256, 4)
void attn_mfma(const _Float16* __restrict__ Qg, const _Float16* __restrict__ Kg,
               const _Float16* __restrict__ Vg, _Float16* __restrict__ Out)
{
    __shared__ _Float16 Qs[64][104];
    __shared__ _Float16 Ks[32][104];
    __shared__ _Float16 Vt[96][40];     // V transposed: Vt[d][k]
    __shared__ _Float16 Pl[4][16][40];  // per-wave P staging

    const int tid  = threadIdx.x;
    const int lane = tid & 63;
    const int wid  = tid >> 6;
    const int lg   = lane >> 4;
    const int li   = lane & 15;

    const int bh = blockIdx.x & 31;
    const int qt_blk = (T / 64 - 1) - (blockIdx.x >> 5);  // heavy tiles first
    const int q0 = qt_blk * 64;
    const int q0w = q0 + wid * 16;

    {
        const u64* src = reinterpret_cast<const u64*>(Qg + ((size_t)bh * T + q0) * HD);
        for (int l = tid; l < 64 * 24; l += 256) {
            const int r = l / 24, c = l % 24;
            *reinterpret_cast<u64*>(&Qs[r][c * 4]) = src[l];
        }
    }
    __syncthreads();

    f16x8 qf[3];
#pragma unroll
    for (int ch = 0; ch < 3; ++ch)
        qf[ch] = *reinterpret_cast<const f16x8*>(
            &Qs[wid * 16 + li][ch * 32 + lg * 8]);

    f32x4 acc[6];
#pragma unroll
    for (int dt = 0; dt < 6; ++dt) acc[dt] = (f32x4)0.f;
    float m_run = -1e30f, l_run = 0.f;

    const int ntiles = q0 / 32 + 2;
    for (int t = 0; t < ntiles; ++t) {
        const int kb = t * 32;
        __syncthreads();
        {
            const u64* src = reinterpret_cast<const u64*>(Kg + ((size_t)bh * T + kb) * HD);
            for (int l = tid; l < 32 * 24; l += 256) {
                const int r = l / 24, c = l % 24;
                *reinterpret_cast<u64*>(&Ks[r][c * 4]) = src[l];
            }
        }
        {
            const u64* src = reinterpret_cast<const u64*>(Vg + ((size_t)bh * T + kb) * HD);
            const int r = tid & 31, cc = tid >> 5;
#pragma unroll
            for (int i = 0; i < 3; ++i) {
                u64 v = src[r * 24 + cc * 3 + i];
                const _Float16* pv = reinterpret_cast<const _Float16*>(&v);
                const int c0 = (cc * 3 + i) * 4;
#pragma unroll
                for (int j = 0; j < 4; ++j) Vt[c0 + j][r] = pv[j];
            }
        }
        __syncthreads();

        if (kb > q0w + 15) continue;   // this wave's rows all above this tile

        f16x8 kf[2][3];
#pragma unroll
        for (int kt = 0; kt < 2; ++kt)
#pragma unroll
            for (int ch = 0; ch < 3; ++ch)
                kf[kt][ch] = *reinterpret_cast<const f16x8*>(
                    &Ks[kt * 16 + li][ch * 32 + lg * 8]);
        f16x8 vf[6];
#pragma unroll
        for (int dt = 0; dt < 6; ++dt)
            vf[dt] = *reinterpret_cast<const f16x8*>(&Vt[dt * 16 + li][lg * 8]);

        // S^T = K @ Q  (scores already in log2 domain; Q pre-scaled)
        f32x4 st[2] = {(f32x4)0.f, (f32x4)0.f};
#pragma unroll
        for (int kt = 0; kt < 2; ++kt)
#pragma unroll
            for (int ch = 0; ch < 3; ++ch)
                st[kt] = __builtin_amdgcn_mfma_f32_16x16x32_f16(
                    kf[kt][ch], qf[ch], st[kt], 0, 0, 0);

        float s[8];
        float m8;
        if (kb + 31 <= q0w) {          // interior: no mask
#pragma unroll
            for (int i = 0; i < 8; ++i) s[i] = st[i >> 2][i & 3];
            m8 = fmaxf(fmaxf(fmaxf(s[0], s[1]), fmaxf(s[2], s[3])),
                       fmaxf(fmaxf(s[4], s[5]), fmaxf(s[6], s[7])));
        } else {                        // diagonal: causal mask
            const int qg = q0w + li;
            m8 = -1e30f;
#pragma unroll
            for (int kt = 0; kt < 2; ++kt)
#pragma unroll
                for (int rr = 0; rr < 4; ++rr) {
                    const int kg = kb + kt * 16 + lg * 4 + rr;
                    const float v = (kg <= qg) ? st[kt][rr] : -1e30f;
                    s[kt * 4 + rr] = v;
                    m8 = fmaxf(m8, v);
                }
        }
        m8 = fmaxf(m8, __shfl_xor(m8, 16));
        m8 = fmaxf(m8, __shfl_xor(m8, 32));

        float p[8], ls;
        if (__all(m8 <= m_run + 8.0f)) {
            // deferred: keep old max, p bounded by 2^8
#pragma unroll
            for (int i = 0; i < 8; ++i) p[i] = __builtin_amdgcn_exp2f(s[i] - m_run);
            ls = ((p[0] + p[1]) + (p[2] + p[3])) + ((p[4] + p[5]) + (p[6] + p[7]));
            ls += __shfl_xor(ls, 16);
            ls += __shfl_xor(ls, 32);
            l_run += ls;
        } else {
            const float m_new = fmaxf(m_run, m8);
            const float corr = __builtin_amdgcn_exp2f(m_run - m_new);
            m_run = m_new;
#pragma unroll
            for (int i = 0; i < 8; ++i) p[i] = __builtin_amdgcn_exp2f(s[i] - m_new);
            ls = ((p[0] + p[1]) + (p[2] + p[3])) + ((p[4] + p[5]) + (p[6] + p[7]));
            ls += __shfl_xor(ls, 16);
            ls += __shfl_xor(ls, 32);
            l_run = l_run * corr + ls;
            float cr[4];
#pragma unroll
            for (int rr = 0; rr < 4; ++rr) cr[rr] = __shfl(corr, lg * 4 + rr);
#pragma unroll
            for (int dt = 0; dt < 6; ++dt)
#pragma unroll
                for (int rr = 0; rr < 4; ++rr) acc[dt][rr] *= cr[rr];
        }

        // stage P (fp16) to wave-private LDS: one u64 per kt
#pragma unroll
        for (int kt = 0; kt < 2; ++kt) {
            f16x4 pk;
            pk[0] = (_Float16)p[kt * 4 + 0]; pk[1] = (_Float16)p[kt * 4 + 1];
            pk[2] = (_Float16)p[kt * 4 + 2]; pk[3] = (_Float16)p[kt * 4 + 3];
            *reinterpret_cast<u64*>(&Pl[wid][li][kt * 16 + lg * 4]) =
                __builtin_bit_cast(u64, pk);
        }

        const f16x8 pf = *reinterpret_cast<const f16x8*>(&Pl[wid][li][lg * 8]);
#pragma unroll
        for (int dt = 0; dt < 6; ++dt)
            acc[dt] = __builtin_amdgcn_mfma_f32_16x16x32_f16(
                pf, vf[dt], acc[dt], 0, 0, 0);
    }

    const int ob = bh >> 3, oh = bh & 7;
#pragma unroll
    for (int rr = 0; rr < 4; ++rr) {
        const float linv = 1.0f / __shfl(l_run, lg * 4 + rr);
        const int qg = q0w + lg * 4 + rr;
        _Float16* op = Out + ((size_t)(ob * T + qg)) * Dm + oh * HD;
#pragma unroll
        for (int dt = 0; dt < 6; ++dt)
            op[dt * 16 + li] = (_Float16)(acc[dt][rr] * linv);
    }
}

// ---------------------------------------------------------------------------
extern "C" void kernel_launch(void* const* d_in, const int* in_sizes, int n_in,
                              void* d_out, int out_size, void* d_ws, size_t ws_size,
                              hipStream_t stream)
{
    const float* x     = (const float*)d_in[0];
    const float* w_qkv = (const float*)d_in[1];
    const float* w_out = (const float*)d_in[2];
    // d_in[3] = leech kernel: orthogonal -> cancels in q.kT, ignored.

    _Float16* qb  = (_Float16*)d_ws;
    _Float16* kb  = qb + QBUF;
    _Float16* vb  = kb + QBUF;
    _Float16* aoh = vb + QBUF;
    _Float16* xh  = aoh + (size_t)Bq * T * Dm;
    _Float16* wqh = xh + (size_t)Bq * T * Dm;
    _Float16* woh = wqh + (size_t)3 * Dm * Dm;
    float* out = (float*)d_out;

    const int M = Bq * T;  // 8192

    cvt_f16<<<dim3((M * Dm) / 4 / 256), dim3(256), 0, stream>>>(x, xh, M * Dm / 4);
    cvt_f16<<<dim3((3 * Dm * Dm) / 4 / 256), dim3(256), 0, stream>>>(w_qkv, wqh, 3 * Dm * Dm / 4);
    cvt_f16<<<dim3((Dm * Dm) / 4 / 256), dim3(256), 0, stream>>>(w_out, woh, Dm * Dm / 4);

    gemm_mfma<true><<<dim3((3 * Dm) / 128, M / 128), dim3(256), 0, stream>>>(
        xh, wqh, qb, nullptr, 3 * Dm);

    attn_mfma<<<dim3(BH * (T / 64)), dim3(256), 0, stream>>>(qb, kb, vb, aoh);

    gemm_mfma<false><<<dim3(Dm / 128, M / 128), dim3(256), 0, stream>>>(
        aoh, woh, nullptr, out, Dm);
}

// Round 5
// 207.895 us; speedup vs baseline: 13.3453x; 1.1145x over previous
//
#include <hip/hip_runtime.h>
#include <cstdint>
#include <cstddef>

#define Bq 4
#define T 2048
#define Dm 768
#define H 8
#define HD 96
#define BH 32
#define QEL ((size_t)BH*T*HD)     // q / v^T element count
#define KEL ((size_t)BH*T*128)    // padded K element count
// q pre-scaled by HD^-0.5 * log2(e): attention uses exp2 directly
#define QS 0.14724703336f
#define KVB 64

typedef unsigned int u32;
typedef unsigned long long u64;
typedef _Float16 f16x8 __attribute__((ext_vector_type(8)));
typedef _Float16 f16x4 __attribute__((ext_vector_type(4)));
typedef float f32x4 __attribute__((ext_vector_type(4)));

// ---------------------------------------------------------------------------
__global__ __launch_bounds__(256)
void cvt_f16(const float* __restrict__ in, _Float16* __restrict__ out, int n4)
{
    const int i = blockIdx.x * 256 + threadIdx.x;
    if (i < n4) {
        const float4 v = reinterpret_cast<const float4*>(in)[i];
        f16x4 h;
        h[0] = (_Float16)v.x; h[1] = (_Float16)v.y;
        h[2] = (_Float16)v.z; h[3] = (_Float16)v.w;
        reinterpret_cast<f16x4*>(out)[i] = h;
    }
}

// ---------------------------------------------------------------------------
// fp16 MFMA GEMM, BM=BN=128, BK=32, 4 waves, 64x64/wave.
// SCATTER=true: q -> qb[bh][t][96] (*QS); k -> kpd[bh][t][128] (d-padded);
//               v -> vtb[bh][d][T] (transposed).
// ---------------------------------------------------------------------------
template <bool SCATTER>
__global__ __launch_bounds__(256)
void gemm_mfma(const _Float16* __restrict__ A, const _Float16* __restrict__ Bw,
               _Float16* __restrict__ qb, _Float16* __restrict__ kpd,
               _Float16* __restrict__ vtb, float* __restrict__ C, int N)
{
    constexpr int K = Dm;
    __shared__ _Float16 As[4 * 128 * 8];
    __shared__ _Float16 Bs[4 * 128 * 8];

    const int tid  = threadIdx.x;
    const int lane = tid & 63;
    const int wid  = tid >> 6;
    const int li   = lane & 15;
    const int lg   = lane >> 4;
    const int wr   = wid >> 1;
    const int wc   = wid & 1;
    const int m0   = blockIdx.y * 128;
    const int n0   = blockIdx.x * 128;

    f32x4 acc[4][4];
#pragma unroll
    for (int i = 0; i < 4; ++i)
#pragma unroll
        for (int j = 0; j < 4; ++j) acc[i][j] = (f32x4)0.f;

    const int s0 = wid * 128 + lane;
    for (int k0 = 0; k0 < K; k0 += 32) {
#pragma unroll
        for (int i = 0; i < 2; ++i) {
            const int s = s0 + i * 64;
            const int row = s & 127, chunk = s >> 7;
            const _Float16* ga = A + (size_t)(m0 + row) * K + k0 + chunk * 8;
            const _Float16* gb = Bw + (size_t)(n0 + row) * K + k0 + chunk * 8;
            __builtin_amdgcn_global_load_lds(
                (const __attribute__((address_space(1))) void*)ga,
                (__attribute__((address_space(3))) void*)&As[(wid * 128 + i * 64) * 8],
                16, 0, 0);
            __builtin_amdgcn_global_load_lds(
                (const __attribute__((address_space(1))) void*)gb,
                (__attribute__((address_space(3))) void*)&Bs[(wid * 128 + i * 64) * 8],
                16, 0, 0);
        }
        __syncthreads();

        f16x8 af[4], bf[4];
#pragma unroll
        for (int i = 0; i < 4; ++i)
            af[i] = *reinterpret_cast<const f16x8*>(
                &As[(lg * 128 + wr * 64 + i * 16 + li) * 8]);
#pragma unroll
        for (int j = 0; j < 4; ++j)
            bf[j] = *reinterpret_cast<const f16x8*>(
                &Bs[(lg * 128 + wc * 64 + j * 16 + li) * 8]);
#pragma unroll
        for (int i = 0; i < 4; ++i)
#pragma unroll
            for (int j = 0; j < 4; ++j)
                acc[i][j] = __builtin_amdgcn_mfma_f32_16x16x32_f16(
                    af[i], bf[j], acc[i][j], 0, 0, 0);
        __syncthreads();
    }

#pragma unroll
    for (int i = 0; i < 4; ++i) {
#pragma unroll
        for (int r = 0; r < 4; ++r) {
            const int m = m0 + wr * 64 + i * 16 + lg * 4 + r;
            if (SCATTER) {
                const int b_ = m >> 11, t_ = m & 2047;
#pragma unroll
                for (int j = 0; j < 4; ++j) {
                    const int e = n0 + wc * 64 + j * 16 + li;
                    const int c = e / Dm;
                    const int rem = e - c * Dm;
                    const int h = rem / HD;
                    const int d = rem - h * HD;
                    const size_t bhx = (size_t)(b_ * H + h);
                    const float v = acc[i][j][r];
                    if (c == 0)
                        qb[(bhx * T + t_) * HD + d] = (_Float16)(v * QS);
                    else if (c == 1)
                        kpd[(bhx * T + t_) * 128 + d] = (_Float16)v;
                    else
                        vtb[(bhx * 96 + d) * T + t_] = (_Float16)v;
                }
            } else {
#pragma unroll
                for (int j = 0; j < 4; ++j) {
                    const int n = n0 + wc * 64 + j * 16 + li;
                    C[(size_t)m * N + n] = acc[i][j][r];
                }
            }
        }
    }
}

// ---------------------------------------------------------------------------
// MFMA flash attention, causal, fp16 in/out. Q pre-scaled (exp2 softmax).
// Block = 4 waves x 16 q rows (QBLK=64); KV tiles of 64, double-buffered with
// counted-vmcnt prefetch (global_load_lds, pre-swizzled source -> XOR-swizzled
// conflict-free ds_read_b128). K from padded [T][128]; V from V^T [96][T].
// ---------------------------------------------------------------------------
__global__ __launch_bounds__(256)
void attn_mfma(const _Float16* __restrict__ QG, const _Float16* __restrict__ KG,
               const _Float16* __restrict__ VtG, _Float16* __restrict__ Out)
{
    __shared__ __align__(16) _Float16 Klds[2][64 * 128];
    __shared__ __align__(16) _Float16 Vlds[2][96 * 64];
    __shared__ __align__(16) _Float16 Pl[4][16][72];

    const int tid  = threadIdx.x;
    const int lane = tid & 63;
    const int wid  = tid >> 6;
    const int lg   = lane >> 4;
    const int li   = lane & 15;

    const int bh     = blockIdx.x & 31;
    const int qt_blk = 31 - (blockIdx.x >> 5);   // heavy q-tiles first
    const int q0     = qt_blk * 64;
    const int q0w    = q0 + wid * 16;
    const int ntiles = qt_blk + 1;

    // Q fragments straight to registers (B-frag: col=li -> q row, k=d)
    f16x8 qf[3];
    {
        const _Float16* qrow = QG + ((size_t)bh * T + q0w + li) * HD;
#pragma unroll
        for (int ch = 0; ch < 3; ++ch)
            qf[ch] = *reinterpret_cast<const f16x8*>(qrow + ch * 32 + lg * 8);
    }

    // stage tile kb into buffer b: K 4x + V 3x global_load_lds per wave,
    // source pre-swizzled so linear LDS dest == swizzled layout.
    const int rK = lane >> 4;                  // 0..3
    const int cK = (lane & 15) * 8;
    const int rV = lane >> 3;                  // 0..7
    const int cV = (lane & 7) * 8;
    auto STAGE = [&](int kb, int b) {
#pragma unroll
        for (int ii = 0; ii < 4; ++ii) {
            const int r  = wid * 16 + ii * 4 + rK;          // row in tile
            const int c0 = cK ^ (((ii * 4 + rK) & 7) << 3); // swizzled src col
            const _Float16* src = KG + ((size_t)(bh * T + kb + r)) * 128 + c0;
            __builtin_amdgcn_global_load_lds(
                (const __attribute__((address_space(1))) void*)src,
                (__attribute__((address_space(3))) void*)&Klds[b][(wid * 16 + ii * 4) * 128],
                16, 0, 0);
        }
#pragma unroll
        for (int jj = 0; jj < 3; ++jj) {
            const int r  = wid * 24 + jj * 8 + rV;          // d row
            const int c0 = cV ^ (rV << 3);
            const _Float16* src = VtG + ((size_t)(bh * 96 + r)) * T + kb + c0;
            __builtin_amdgcn_global_load_lds(
                (const __attribute__((address_space(1))) void*)src,
                (__attribute__((address_space(3))) void*)&Vlds[b][(wid * 24 + jj * 8) * 64],
                16, 0, 0);
        }
    };

    f32x4 acc[6];
#pragma unroll
    for (int dt = 0; dt < 6; ++dt) acc[dt] = (f32x4)0.f;
    float m_run = -1e30f, l_run = 0.f;

    STAGE(0, 0);
    int p = 0;
    for (int t = 0; t < ntiles; ++t) {
        const int kb = t * KVB;
        const bool has_next = (t + 1 < ntiles);
        if (has_next) {
            STAGE(kb + KVB, p ^ 1);
            asm volatile("s_waitcnt vmcnt(7)" ::: "memory");   // buf[p] done
        } else {
            asm volatile("s_waitcnt vmcnt(0)" ::: "memory");
        }
        __builtin_amdgcn_s_barrier();

        // per-wave causal bound: # of 16-row K sub-tiles with any valid k
        const int nkt = min(4, ((q0w + 15 - kb) >> 4) + 1);

        // K A-frags (row=li -> k row, k=d), swizzled read
        f16x8 kf[4][3];
#pragma unroll
        for (int kt = 0; kt < 4; ++kt)
            if (kt < nkt) {
#pragma unroll
                for (int ch = 0; ch < 3; ++ch) {
                    const int row = kt * 16 + li;
                    const int cs  = (ch * 32 + lg * 8) ^ ((row & 7) << 3);
                    kf[kt][ch] = *reinterpret_cast<const f16x8*>(
                        &Klds[p][row * 128 + cs]);
                }
            }

        // S^T = K @ Q
        f32x4 st[4];
#pragma unroll
        for (int kt = 0; kt < 4; ++kt) {
            st[kt] = (f32x4)0.f;
            if (kt < nkt) {
#pragma unroll
                for (int ch = 0; ch < 3; ++ch)
                    st[kt] = __builtin_amdgcn_mfma_f32_16x16x32_f16(
                        kf[kt][ch], qf[ch], st[kt], 0, 0, 0);
            }
        }

        // mask + row max (q = q0w + li; k = kb + kt*16 + lg*4 + rr)
        const int qg = q0w + li;
        float s[16];
        float m16 = -1e30f;
#pragma unroll
        for (int kt = 0; kt < 4; ++kt)
            if (kt < nkt) {
                const bool full = (kb + kt * 16 + 15 <= q0w);
#pragma unroll
                for (int rr = 0; rr < 4; ++rr) {
                    float v = st[kt][rr];
                    if (!full) {
                        const int kg = kb + kt * 16 + lg * 4 + rr;
                        v = (kg <= qg) ? v : -1e30f;
                    }
                    s[kt * 4 + rr] = v;
                    m16 = fmaxf(m16, v);
                }
            }
        m16 = fmaxf(m16, __shfl_xor(m16, 16));
        m16 = fmaxf(m16, __shfl_xor(m16, 32));

        // defer-max: rescale only when max grew by > 8 (log2 domain)
        if (!__all(m16 <= m_run + 8.0f)) {
            const float m_new = fmaxf(m_run, m16);
            const float corr  = __builtin_amdgcn_exp2f(m_run - m_new);
            l_run *= corr;
            float cr[4];
#pragma unroll
            for (int rr = 0; rr < 4; ++rr) cr[rr] = __shfl(corr, lg * 4 + rr);
#pragma unroll
            for (int dt = 0; dt < 6; ++dt)
#pragma unroll
                for (int rr = 0; rr < 4; ++rr) acc[dt][rr] *= cr[rr];
            m_run = m_new;
        }

        float pr[16], ls = 0.f;
#pragma unroll
        for (int kt = 0; kt < 4; ++kt)
            if (kt < nkt) {
#pragma unroll
                for (int rr = 0; rr < 4; ++rr) {
                    pr[kt * 4 + rr] = __builtin_amdgcn_exp2f(s[kt * 4 + rr] - m_run);
                    ls += pr[kt * 4 + rr];
                }
            }
        ls += __shfl_xor(ls, 16);
        ls += __shfl_xor(ls, 32);
        l_run += ls;

        // stage P to wave-private LDS (u64 per sub-tile); zero odd remainder
#pragma unroll
        for (int kt = 0; kt < 4; ++kt)
            if (kt < nkt) {
                f16x4 pk;
                pk[0] = (_Float16)pr[kt * 4 + 0]; pk[1] = (_Float16)pr[kt * 4 + 1];
                pk[2] = (_Float16)pr[kt * 4 + 2]; pk[3] = (_Float16)pr[kt * 4 + 3];
                *reinterpret_cast<u64*>(&Pl[wid][li][kt * 16 + lg * 4]) =
                    __builtin_bit_cast(u64, pk);
            }
        if (nkt & 1)
            *reinterpret_cast<u64*>(&Pl[wid][li][nkt * 16 + lg * 4]) = 0ull;

        // PV: per 32-k chunk, A=P frag, B=V frag (row=d, swizzled read)
        const int npc = (nkt + 1) >> 1;
#pragma unroll
        for (int pc = 0; pc < 2; ++pc)
            if (pc < npc) {
                const f16x8 pf = *reinterpret_cast<const f16x8*>(
                    &Pl[wid][li][pc * 32 + lg * 8]);
#pragma unroll
                for (int dt = 0; dt < 6; ++dt) {
                    const int row = dt * 16 + li;
                    const int cs  = (pc * 32 + lg * 8) ^ ((row & 7) << 3);
                    const f16x8 vf = *reinterpret_cast<const f16x8*>(
                        &Vlds[p][row * 64 + cs]);
                    acc[dt] = __builtin_amdgcn_mfma_f32_16x16x32_f16(
                        pf, vf, acc[dt], 0, 0, 0);
                }
            }

        asm volatile("s_waitcnt lgkmcnt(0)" ::: "memory");
        __builtin_amdgcn_s_barrier();   // all reads of buf[p] done
        p ^= 1;
    }

    // epilogue: normalize, store fp16 to ao[B][T][768]
    const int ob = bh >> 3, oh = bh & 7;
#pragma unroll
    for (int rr = 0; rr < 4; ++rr) {
        const float linv = 1.0f / __shfl(l_run, lg * 4 + rr);
        const int qg2 = q0w + lg * 4 + rr;
        _Float16* op = Out + ((size_t)(ob * T + qg2)) * Dm + oh * HD;
#pragma unroll
        for (int dt = 0; dt < 6; ++dt)
            op[dt * 16 + li] = (_Float16)(acc[dt][rr] * linv);
    }
}

// ---------------------------------------------------------------------------
extern "C" void kernel_launch(void* const* d_in, const int* in_sizes, int n_in,
                              void* d_out, int out_size, void* d_ws, size_t ws_size,
                              hipStream_t stream)
{
    const float* x     = (const float*)d_in[0];
    const float* w_qkv = (const float*)d_in[1];
    const float* w_out = (const float*)d_in[2];
    // d_in[3] = leech kernel: orthogonal -> cancels in q.kT, ignored.

    _Float16* qb  = (_Float16*)d_ws;                 // [BH][T][96]
    _Float16* kpd = qb + QEL;                        // [BH][T][128]
    _Float16* vtb = kpd + KEL;                       // [BH][96][T]
    _Float16* aoh = vtb + QEL;                       // [B*T][768]
    _Float16* xh  = aoh + (size_t)Bq * T * Dm;
    _Float16* wqh = xh + (size_t)Bq * T * Dm;
    _Float16* woh = wqh + (size_t)3 * Dm * Dm;
    float* out = (float*)d_out;

    const int M = Bq * T;  // 8192

    cvt_f16<<<dim3((M * Dm) / 4 / 256), dim3(256), 0, stream>>>(x, xh, M * Dm / 4);
    cvt_f16<<<dim3((3 * Dm * Dm) / 4 / 256), dim3(256), 0, stream>>>(w_qkv, wqh, 3 * Dm * Dm / 4);
    cvt_f16<<<dim3((Dm * Dm) / 4 / 256), dim3(256), 0, stream>>>(w_out, woh, Dm * Dm / 4);

    gemm_mfma<true><<<dim3((3 * Dm) / 128, M / 128), dim3(256), 0, stream>>>(
        xh, wqh, qb, kpd, vtb, nullptr, 3 * Dm);

    attn_mfma<<<dim3(BH * (T / 64)), dim3(256), 0, stream>>>(qb, kpd, vtb, aoh);

    gemm_mfma<false><<<dim3(Dm / 128, M / 128), dim3(256), 0, stream>>>(
        aoh, woh, nullptr, nullptr, nullptr, out, Dm);
}